// Round 2
// baseline (657.499 us; speedup 1.0000x reference)
//
#include <hip/hip_runtime.h>
#include <cstddef>
#include <cstdint>

#define IN_F 512
#define OUT_F 128
#define NREL 10
#define BM 64
#define BK 16

// relation tables (from the reference RELS/EDGES)
static const int kNSrc[NREL]   = {8000,16000,8000,16000,8000,4000,8000,4000,16000,4000};
static const int kNDst[NREL]   = {8000,16000,16000,8000,4000,8000,4000,8000,4000,16000};
static const int kNEdges[NREL] = {200000,800000,400000,400000,100000,100000,100000,100000,150000,150000};
static const int kRelSrcType[NREL] = {0,1,0,1,0,2,0,3,1,2};
static const int kNNodes[4] = {8000,16000,4000,4000};
static const size_t kOutOff[4] = {0, 8000ull*OUT_F, 24000ull*OUT_F, 28000ull*OUT_F};
// relations whose dst is each type
static const int kDstRels[4][4] = {{0,3,5,7},{1,2,9,-1},{4,8,-1,-1},{6,-1,-1,-1}};
static const int kNDstRels[4] = {4,3,2,1};

// ---------------- degree histogram ----------------
struct DegRel { const int* src; const int* dst; int* deg_out; int* deg_in; int n_edges; };
struct DegParams { DegRel r[NREL]; };

__global__ __launch_bounds__(256) void k_degree(DegParams p) {
  DegRel R = p.r[blockIdx.y];
  int e = blockIdx.x * 256 + threadIdx.x;
  if (e >= R.n_edges) return;
  atomicAdd(R.deg_out + R.src[e], 1);
  atomicAdd(R.deg_in + R.dst[e], 1);
}

// ---------------- exclusive scan (one block per relation) ----------------
struct ScanRel { const int* deg_in; int* rowstart; int* cursor; int n; };
struct ScanParams { ScanRel r[NREL]; };

__global__ __launch_bounds__(1024) void k_scan(ScanParams p) {
  ScanRel R = p.r[blockIdx.x];
  __shared__ int sm[1024];
  const int t = threadIdx.x;
  int carry = 0;
  for (int base = 0; base < R.n; base += 1024) {
    int i = base + t;
    int v = (i < R.n) ? R.deg_in[i] : 0;
    sm[t] = v;
    __syncthreads();
    for (int off = 1; off < 1024; off <<= 1) {
      int add = (t >= off) ? sm[t - off] : 0;
      __syncthreads();
      sm[t] += add;
      __syncthreads();
    }
    int excl = carry + sm[t] - v;   // exclusive prefix
    if (i < R.n) { R.rowstart[i] = excl; R.cursor[i] = excl; }
    carry += sm[1023];
    __syncthreads();
  }
  if (t == 0) R.rowstart[R.n] = carry;
}

// ---------------- CSR fill (counting sort by dst) ----------------
struct FillRel { const int* src; const int* dst; int* cursor; int* csr; int n_edges; };
struct FillParams { FillRel r[NREL]; };

__global__ __launch_bounds__(256) void k_fill(FillParams p) {
  FillRel R = p.r[blockIdx.y];
  int e = blockIdx.x * 256 + threadIdx.x;
  if (e >= R.n_edges) return;
  int pos = atomicAdd(R.cursor + R.dst[e], 1);
  R.csr[pos] = R.src[e];
}

// ---------------- y_r = (h @ W_r) * deg_out^-1/2 ----------------
struct GemmRel { const float* h; const float* W; float* y; const int* deg_out; int n_src; };
struct GemmParams { GemmRel r[NREL]; };

__global__ __launch_bounds__(256) void k_gemm(GemmParams p) {
  GemmRel R = p.r[blockIdx.y];
  const int m0 = blockIdx.x * BM;
  if (m0 >= R.n_src) return;
  __shared__ float As[BK][BM];      // transposed A tile: As[k][m]
  __shared__ float Bs[BK][OUT_F];   // Bs[k][n]
  const int t = threadIdx.x;
  const int tm = t >> 5, tn = t & 31;             // micro-tile: 8 rows x 4 cols
  const int arow = t >> 2, acol = (t & 3) << 2;   // A staging: row t/4, 4 cols
  const int brow = t >> 4, bcol = (t & 15) << 3;  // B staging: row t/16, 8 cols
  float acc[8][4] = {};
  for (int k0 = 0; k0 < IN_F; k0 += BK) {
    float4 av = make_float4(0.f, 0.f, 0.f, 0.f);
    const int gr = m0 + arow;
    if (gr < R.n_src) av = *(const float4*)(R.h + (size_t)gr * IN_F + k0 + acol);
    const float4 bv0 = *(const float4*)(R.W + (size_t)(k0 + brow) * OUT_F + bcol);
    const float4 bv1 = *(const float4*)(R.W + (size_t)(k0 + brow) * OUT_F + bcol + 4);
    __syncthreads();
    As[acol + 0][arow] = av.x;
    As[acol + 1][arow] = av.y;
    As[acol + 2][arow] = av.z;
    As[acol + 3][arow] = av.w;
    *(float4*)&Bs[brow][bcol] = bv0;
    *(float4*)&Bs[brow][bcol + 4] = bv1;
    __syncthreads();
#pragma unroll
    for (int k = 0; k < BK; ++k) {
      float a[8], bb[4];
#pragma unroll
      for (int i = 0; i < 8; ++i) a[i] = As[k][tm * 8 + i];
#pragma unroll
      for (int j = 0; j < 4; ++j) bb[j] = Bs[k][tn * 4 + j];
#pragma unroll
      for (int i = 0; i < 8; ++i)
#pragma unroll
        for (int j = 0; j < 4; ++j)
          acc[i][j] = fmaf(a[i], bb[j], acc[i][j]);
    }
  }
#pragma unroll
  for (int i = 0; i < 8; ++i) {
    const int gr = m0 + tm * 8 + i;
    if (gr < R.n_src) {
      const int d = R.deg_out[gr];
      const float s = rsqrtf((float)(d > 1 ? d : 1));
      float4 v;
      v.x = acc[i][0] * s; v.y = acc[i][1] * s; v.z = acc[i][2] * s; v.w = acc[i][3] * s;
      *(float4*)(R.y + (size_t)gr * OUT_F + tn * 4) = v;
    }
  }
}

// ---------------- gather-aggregate + bias + relu (one wave per dst node) ----------------
struct AggRel { const int* rowstart; const int* csr; const float* y; const int* deg_in; const float* b; };
struct AggType { AggRel r[4]; int n_rels; int n_nodes; float* out; };
struct AggParams { AggType t[4]; };

__global__ __launch_bounds__(64) void k_aggregate(AggParams p) {
  const AggType& T = p.t[blockIdx.y];
  const int node = blockIdx.x;
  if (node >= T.n_nodes) return;
  const int lane = threadIdx.x;
  float ox = 0.f, oy = 0.f;
#pragma unroll
  for (int rr = 0; rr < 4; ++rr) {
    if (rr < T.n_rels) {
      const AggRel& R = T.r[rr];
      const int lo = R.rowstart[node];
      const int hi = R.rowstart[node + 1];
      float ax = 0.f, ay = 0.f;
      int k = lo;
      for (; k + 4 <= hi; k += 4) {
        const int s0 = R.csr[k], s1 = R.csr[k + 1], s2 = R.csr[k + 2], s3 = R.csr[k + 3];
        const float2 v0 = *(const float2*)(R.y + (size_t)s0 * OUT_F + lane * 2);
        const float2 v1 = *(const float2*)(R.y + (size_t)s1 * OUT_F + lane * 2);
        const float2 v2 = *(const float2*)(R.y + (size_t)s2 * OUT_F + lane * 2);
        const float2 v3 = *(const float2*)(R.y + (size_t)s3 * OUT_F + lane * 2);
        ax += v0.x + v1.x + v2.x + v3.x;
        ay += v0.y + v1.y + v2.y + v3.y;
      }
      for (; k < hi; ++k) {
        const int s0 = R.csr[k];
        const float2 v0 = *(const float2*)(R.y + (size_t)s0 * OUT_F + lane * 2);
        ax += v0.x; ay += v0.y;
      }
      const int d = R.deg_in[node];
      const float s = rsqrtf((float)(d > 1 ? d : 1));
      const float2 bb = *(const float2*)(R.b + lane * 2);
      ox += ax * s + bb.x;
      oy += ay * s + bb.y;
    }
  }
  float2 o;
  o.x = ox > 0.f ? ox : 0.f;
  o.y = oy > 0.f ? oy : 0.f;
  *(float2*)(T.out + (size_t)node * OUT_F + lane * 2) = o;
}

// ---------------- host ----------------
extern "C" void kernel_launch(void* const* d_in, const int* in_sizes, int n_in,
                              void* d_out, int out_size, void* d_ws, size_t ws_size,
                              hipStream_t stream) {
  const float* h[4];
  for (int i = 0; i < 4; ++i) h[i] = (const float*)d_in[i];
  const float* W[NREL]; const float* b[NREL];
  const int* src[NREL]; const int* dst[NREL];
  for (int r = 0; r < NREL; ++r) {
    W[r]   = (const float*)d_in[4 + 2 * r];
    b[r]   = (const float*)d_in[5 + 2 * r];
    src[r] = (const int*)d_in[24 + 2 * r];
    dst[r] = (const int*)d_in[25 + 2 * r];
  }
  float* out = (float*)d_out;

  // carve workspace (~59 MB)
  char* ws = (char*)d_ws;
  size_t off = 0;
  auto alloc = [&](size_t bytes) -> char* {
    char* p = ws + off;
    off = (off + bytes + 255) & ~(size_t)255;
    return p;
  };
  int* degO[NREL]; int* degI[NREL];
  char* degbase = alloc((size_t)184000 * 4);
  {
    size_t o = 0;
    for (int r = 0; r < NREL; ++r) { degO[r] = (int*)(degbase + o); o += (size_t)kNSrc[r] * 4; }
    for (int r = 0; r < NREL; ++r) { degI[r] = (int*)(degbase + o); o += (size_t)kNDst[r] * 4; }
  }
  int* rowst[NREL];
  { char* base = alloc((size_t)(92000 + NREL) * 4); size_t o = 0;
    for (int r = 0; r < NREL; ++r) { rowst[r] = (int*)(base + o); o += (size_t)(kNDst[r] + 1) * 4; } }
  int* cur[NREL];
  { char* base = alloc((size_t)92000 * 4); size_t o = 0;
    for (int r = 0; r < NREL; ++r) { cur[r] = (int*)(base + o); o += (size_t)kNDst[r] * 4; } }
  int* csr[NREL];
  { char* base = alloc((size_t)2500000 * 4); size_t o = 0;
    for (int r = 0; r < NREL; ++r) { csr[r] = (int*)(base + o); o += (size_t)kNEdges[r] * 4; } }
  float* y[NREL];
  { char* base = alloc((size_t)92000 * OUT_F * 4); size_t o = 0;
    for (int r = 0; r < NREL; ++r) { y[r] = (float*)(base + o); o += (size_t)kNSrc[r] * OUT_F * 4; } }

  hipMemsetAsync(degbase, 0, (size_t)184000 * 4, stream);

  DegParams dp;
  for (int r = 0; r < NREL; ++r) dp.r[r] = DegRel{src[r], dst[r], degO[r], degI[r], kNEdges[r]};
  k_degree<<<dim3((800000 + 255) / 256, NREL), 256, 0, stream>>>(dp);

  ScanParams sp;
  for (int r = 0; r < NREL; ++r) sp.r[r] = ScanRel{degI[r], rowst[r], cur[r], kNDst[r]};
  k_scan<<<NREL, 1024, 0, stream>>>(sp);

  FillParams fp;
  for (int r = 0; r < NREL; ++r) fp.r[r] = FillRel{src[r], dst[r], cur[r], csr[r], kNEdges[r]};
  k_fill<<<dim3((800000 + 255) / 256, NREL), 256, 0, stream>>>(fp);

  GemmParams gp;
  for (int r = 0; r < NREL; ++r) gp.r[r] = GemmRel{h[kRelSrcType[r]], W[r], y[r], degO[r], kNSrc[r]};
  k_gemm<<<dim3((16000 + BM - 1) / BM, NREL), 256, 0, stream>>>(gp);

  AggParams ap;
  for (int ti = 0; ti < 4; ++ti) {
    AggType& T = ap.t[ti];
    T.n_nodes = kNNodes[ti];
    T.n_rels = kNDstRels[ti];
    T.out = out + kOutOff[ti];
    for (int j = 0; j < 4; ++j) {
      int r = kDstRels[ti][j];
      if (r < 0) r = kDstRels[ti][0];  // padding with a valid (unused) descriptor
      T.r[j] = AggRel{rowst[r], csr[r], y[r], degI[r], b[r]};
    }
  }
  k_aggregate<<<dim3(16000, 4), 64, 0, stream>>>(ap);
}

// Round 3
// 355.169 us; speedup vs baseline: 1.8512x; 1.8512x over previous
//
#include <hip/hip_runtime.h>
#include <cstddef>
#include <cstdint>

#define IN_F 512
#define OUT_F 128
#define NREL 10
#define MAXBINS 16000
#define HCHUNK 131072

typedef __attribute__((ext_vector_type(8))) short short8;
typedef __attribute__((ext_vector_type(4))) float f32x4;

static const int kNSrc[NREL]   = {8000,16000,8000,16000,8000,4000,8000,4000,16000,4000};
static const int kNDst[NREL]   = {8000,16000,16000,8000,4000,8000,4000,8000,4000,16000};
static const int kNEdges[NREL] = {200000,800000,400000,400000,100000,100000,100000,100000,150000,150000};
static const int kRelSrcType[NREL] = {0,1,0,1,0,2,0,3,1,2};
static const int kNNodes[4] = {8000,16000,4000,4000};
static const size_t kOutOff[4] = {0, 8000ull*OUT_F, 24000ull*OUT_F, 28000ull*OUT_F};
static const int kDstRels[4][4] = {{0,3,5,7},{1,2,9,-1},{4,8,-1,-1},{6,-1,-1,-1}};
static const int kNDstRels[4] = {4,3,2,1};

__device__ __forceinline__ unsigned short f2bf(float f) {
  union { float f; unsigned u; } v; v.f = f;
  unsigned r = v.u + 0x7fffu + ((v.u >> 16) & 1u);
  return (unsigned short)(r >> 16);
}
__device__ __forceinline__ float bf2f(unsigned short b) {
  union { unsigned u; float f; } v; v.u = ((unsigned)b) << 16;
  return v.f;
}

// ---------------- LDS-privatized histogram (jobs: 0..9 src, 10..19 dst) ----------------
struct HistJob { const int* idx; int* deg; int n_edges; int nbins; };
struct HistParams { HistJob j[2 * NREL]; };

__global__ __launch_bounds__(1024) void k_hist(HistParams p) {
  HistJob J = p.j[blockIdx.y];
  const int e0 = blockIdx.x * HCHUNK;
  if (e0 >= J.n_edges) return;
  __shared__ int lb[MAXBINS];
  const int t = threadIdx.x;
  for (int d = t; d < J.nbins; d += 1024) lb[d] = 0;
  __syncthreads();
  const int eend = (e0 + HCHUNK < J.n_edges) ? e0 + HCHUNK : J.n_edges;
  for (int e = e0 + t; e < eend; e += 1024) atomicAdd(&lb[J.idx[e]], 1);
  __syncthreads();
  for (int d = t; d < J.nbins; d += 1024) {
    int c = lb[d];
    if (c) atomicAdd(&J.deg[d], c);
  }
}

// ---------------- exclusive scan (one 512-thread block per relation, n<=16384) --------
struct ScanRel { const int* deg_in; int* rowstart; int* cursor; int n; };
struct ScanParams { ScanRel r[NREL]; };

__global__ __launch_bounds__(512) void k_scan(ScanParams p) {
  ScanRel R = p.r[blockIdx.x];
  const int t = threadIdx.x;
  const int lane = t & 63, wv = t >> 6;
  const int base = t * 32;
  int v[32];
  int s = 0;
#pragma unroll
  for (int i = 0; i < 32; ++i) {
    int e = base + i;
    int x = (e < R.n) ? R.deg_in[e] : 0;
    v[i] = s; s += x;
  }
  int inc = s;
#pragma unroll
  for (int off = 1; off < 64; off <<= 1) {
    int u = __shfl_up(inc, off);
    if (lane >= off) inc += u;
  }
  __shared__ int wsum[8];
  if (lane == 63) wsum[wv] = inc;
  __syncthreads();
  int carry = 0, total = 0;
#pragma unroll
  for (int w = 0; w < 8; ++w) {
    int x = wsum[w];
    if (w < wv) carry += x;
    total += x;
  }
  const int tb = carry + (inc - s);
#pragma unroll
  for (int i = 0; i < 32; ++i) {
    int e = base + i;
    if (e < R.n) { int val = tb + v[i]; R.rowstart[e] = val; R.cursor[e] = val; }
  }
  if (t == 0) R.rowstart[R.n] = total;
}

// ---------------- LDS-binned CSR fill (bulk reservation, no per-edge global atomics) --
struct FillRel { const int* src; const int* dst; int* cursor; int* csr; int n_edges; int nbins; };
struct FillParams { FillRel r[NREL]; };

__global__ __launch_bounds__(1024) void k_fill(FillParams p) {
  FillRel R = p.r[blockIdx.y];
  const int e0 = blockIdx.x * HCHUNK;
  if (e0 >= R.n_edges) return;
  __shared__ int lb[MAXBINS];
  const int t = threadIdx.x;
  for (int d = t; d < R.nbins; d += 1024) lb[d] = 0;
  __syncthreads();
  const int eend = (e0 + HCHUNK < R.n_edges) ? e0 + HCHUNK : R.n_edges;
  for (int e = e0 + t; e < eend; e += 1024) atomicAdd(&lb[R.dst[e]], 1);
  __syncthreads();
  for (int d = t; d < R.nbins; d += 1024) {
    int c = lb[d];
    if (c) lb[d] = atomicAdd(&R.cursor[d], c);  // replace count with global base
  }
  __syncthreads();
  for (int e = e0 + t; e < eend; e += 1024) {
    int d = R.dst[e];
    int pos = atomicAdd(&lb[d], 1);
    R.csr[pos] = R.src[e];
  }
}

// ---------------- W -> W^T bf16 ----------------
struct WtParams { const float* W[NREL]; unsigned short* WT[NREL]; };

__global__ __launch_bounds__(256) void k_wt(WtParams p) {
  const int r = blockIdx.y;
  const int g = blockIdx.x * 256 + threadIdx.x;  // 0..16383
  const int k = g >> 5;
  const int n0 = (g & 31) * 4;
  const float4 w = *(const float4*)(p.W[r] + (size_t)k * OUT_F + n0);
  unsigned short* WT = p.WT[r];
  WT[(size_t)(n0 + 0) * IN_F + k] = f2bf(w.x);
  WT[(size_t)(n0 + 1) * IN_F + k] = f2bf(w.y);
  WT[(size_t)(n0 + 2) * IN_F + k] = f2bf(w.z);
  WT[(size_t)(n0 + 3) * IN_F + k] = f2bf(w.w);
}

// ---------------- y_r = (h @ W_r) * deg_out^-1/2, bf16 MFMA ----------------
struct GemmRel { const float* h; const unsigned short* WT; unsigned short* y; const int* deg_out; int n_src; };
struct GemmParams { GemmRel r[NREL]; };

__global__ __launch_bounds__(256) void k_gemm(GemmParams p) {
  GemmRel R = p.r[blockIdx.y];
  const int m0 = blockIdx.x * 128;
  if (m0 >= R.n_src) return;
  __shared__ unsigned short As[128][40];  // [m][k], padded row 80B (2-way bank, free)
  __shared__ unsigned short Bs[128][40];  // [n][k]
  const int t = threadIdx.x;
  const int lane = t & 63, wid = t >> 6;
  const int wm = (wid >> 1) * 64, wn = (wid & 1) * 64;
  const int l16 = lane & 15, lk = (lane >> 4) * 8;
  const int arow = t >> 1;            // 0..127
  const int akoff = (t & 1) * 16;     // 0 or 16
  const int grA = m0 + arow;
  const bool avalid = grA < R.n_src;
  const float* hrow = R.h + (size_t)grA * IN_F;
  const unsigned short* wrow = R.WT + (size_t)arow * IN_F;

  f32x4 acc[4][4];
#pragma unroll
  for (int i = 0; i < 4; ++i)
#pragma unroll
    for (int j = 0; j < 4; ++j) acc[i][j] = (f32x4){0.f, 0.f, 0.f, 0.f};

  for (int k0 = 0; k0 < IN_F; k0 += 32) {
    float4 a0, a1, a2, a3;
    if (avalid) {
      a0 = *(const float4*)(hrow + k0 + akoff);
      a1 = *(const float4*)(hrow + k0 + akoff + 4);
      a2 = *(const float4*)(hrow + k0 + akoff + 8);
      a3 = *(const float4*)(hrow + k0 + akoff + 12);
    } else {
      a0 = a1 = a2 = a3 = make_float4(0.f, 0.f, 0.f, 0.f);
    }
    uint4 bv0 = *(const uint4*)(wrow + k0 + akoff);
    uint4 bv1 = *(const uint4*)(wrow + k0 + akoff + 8);

    uint4 A0, A1;
    A0.x = (unsigned)f2bf(a0.x) | ((unsigned)f2bf(a0.y) << 16);
    A0.y = (unsigned)f2bf(a0.z) | ((unsigned)f2bf(a0.w) << 16);
    A0.z = (unsigned)f2bf(a1.x) | ((unsigned)f2bf(a1.y) << 16);
    A0.w = (unsigned)f2bf(a1.z) | ((unsigned)f2bf(a1.w) << 16);
    A1.x = (unsigned)f2bf(a2.x) | ((unsigned)f2bf(a2.y) << 16);
    A1.y = (unsigned)f2bf(a2.z) | ((unsigned)f2bf(a2.w) << 16);
    A1.z = (unsigned)f2bf(a3.x) | ((unsigned)f2bf(a3.y) << 16);
    A1.w = (unsigned)f2bf(a3.z) | ((unsigned)f2bf(a3.w) << 16);

    __syncthreads();  // previous iter's fragment reads done before overwrite
    *(uint4*)&As[arow][akoff] = A0;
    *(uint4*)&As[arow][akoff + 8] = A1;
    *(uint4*)&Bs[arow][akoff] = bv0;
    *(uint4*)&Bs[arow][akoff + 8] = bv1;
    __syncthreads();

    short8 af[4], bfr[4];
#pragma unroll
    for (int f = 0; f < 4; ++f) af[f] = *(const short8*)&As[wm + f * 16 + l16][lk];
#pragma unroll
    for (int f = 0; f < 4; ++f) bfr[f] = *(const short8*)&Bs[wn + f * 16 + l16][lk];
#pragma unroll
    for (int i = 0; i < 4; ++i)
#pragma unroll
      for (int j = 0; j < 4; ++j)
        acc[i][j] = __builtin_amdgcn_mfma_f32_16x16x32_bf16(af[i], bfr[j], acc[i][j], 0, 0, 0);
  }

  const int r4 = (lane >> 4) * 4;  // C/D: col=lane&15, row=(lane>>4)*4+q (m89-verified)
#pragma unroll
  for (int i = 0; i < 4; ++i) {
#pragma unroll
    for (int q = 0; q < 4; ++q) {
      const int row = m0 + wm + i * 16 + r4 + q;
      if (row < R.n_src) {
        const int d = R.deg_out[row];
        const float s = rsqrtf((float)(d > 1 ? d : 1));
#pragma unroll
        for (int j = 0; j < 4; ++j) {
          const int col = wn + j * 16 + l16;
          R.y[(size_t)row * OUT_F + col] = f2bf(acc[i][j][q] * s);
        }
      }
    }
  }
}

// ---------------- gather-aggregate + bias + relu (one wave per dst node) -------------
struct AggRel { const int* rowstart; const int* csr; const unsigned short* y; const float* b; };
struct AggType { AggRel r[4]; int n_rels; int n_nodes; float* out; };
struct AggParams { AggType t[4]; };

__global__ __launch_bounds__(64) void k_aggregate(AggParams p) {
  const AggType& T = p.t[blockIdx.y];
  const int node = blockIdx.x;
  if (node >= T.n_nodes) return;
  const int lane = threadIdx.x;
  const int co = lane * 2;
  float ox = 0.f, oy = 0.f;
#pragma unroll
  for (int rr = 0; rr < 4; ++rr) {
    if (rr < T.n_rels) {
      const AggRel& R = T.r[rr];
      const int lo = R.rowstart[node];
      const int hi = R.rowstart[node + 1];
      float ax = 0.f, ay = 0.f;
      int k = lo;
      for (; k + 4 <= hi; k += 4) {
        const int s0 = R.csr[k], s1 = R.csr[k + 1], s2 = R.csr[k + 2], s3 = R.csr[k + 3];
        const unsigned u0 = *(const unsigned*)(R.y + (size_t)s0 * OUT_F + co);
        const unsigned u1 = *(const unsigned*)(R.y + (size_t)s1 * OUT_F + co);
        const unsigned u2 = *(const unsigned*)(R.y + (size_t)s2 * OUT_F + co);
        const unsigned u3 = *(const unsigned*)(R.y + (size_t)s3 * OUT_F + co);
        ax += bf2f((unsigned short)u0) + bf2f((unsigned short)u1) +
              bf2f((unsigned short)u2) + bf2f((unsigned short)u3);
        ay += bf2f((unsigned short)(u0 >> 16)) + bf2f((unsigned short)(u1 >> 16)) +
              bf2f((unsigned short)(u2 >> 16)) + bf2f((unsigned short)(u3 >> 16));
      }
      for (; k < hi; ++k) {
        const int s0 = R.csr[k];
        const unsigned u0 = *(const unsigned*)(R.y + (size_t)s0 * OUT_F + co);
        ax += bf2f((unsigned short)u0);
        ay += bf2f((unsigned short)(u0 >> 16));
      }
      const int deg = hi - lo;
      const float s = rsqrtf((float)(deg > 1 ? deg : 1));
      const float2 bb = *(const float2*)(R.b + co);
      ox += ax * s + bb.x;
      oy += ay * s + bb.y;
    }
  }
  float2 o;
  o.x = ox > 0.f ? ox : 0.f;
  o.y = oy > 0.f ? oy : 0.f;
  *(float2*)(T.out + (size_t)node * OUT_F + co) = o;
}

// ---------------- host ----------------
extern "C" void kernel_launch(void* const* d_in, const int* in_sizes, int n_in,
                              void* d_out, int out_size, void* d_ws, size_t ws_size,
                              hipStream_t stream) {
  const float* h[4];
  for (int i = 0; i < 4; ++i) h[i] = (const float*)d_in[i];
  const float* W[NREL]; const float* b[NREL];
  const int* src[NREL]; const int* dst[NREL];
  for (int r = 0; r < NREL; ++r) {
    W[r]   = (const float*)d_in[4 + 2 * r];
    b[r]   = (const float*)d_in[5 + 2 * r];
    src[r] = (const int*)d_in[24 + 2 * r];
    dst[r] = (const int*)d_in[25 + 2 * r];
  }
  float* out = (float*)d_out;

  char* ws = (char*)d_ws;
  size_t off = 0;
  auto alloc = [&](size_t bytes) -> char* {
    char* p = ws + off;
    off = (off + bytes + 255) & ~(size_t)255;
    return p;
  };
  int* degO[NREL]; int* degI[NREL];
  char* degbase = alloc((size_t)184000 * 4);
  {
    size_t o = 0;
    for (int r = 0; r < NREL; ++r) { degO[r] = (int*)(degbase + o); o += (size_t)kNSrc[r] * 4; }
    for (int r = 0; r < NREL; ++r) { degI[r] = (int*)(degbase + o); o += (size_t)kNDst[r] * 4; }
  }
  int* rowst[NREL];
  { char* base = alloc((size_t)(92000 + NREL) * 4); size_t o = 0;
    for (int r = 0; r < NREL; ++r) { rowst[r] = (int*)(base + o); o += (size_t)(kNDst[r] + 1) * 4; } }
  int* cur[NREL];
  { char* base = alloc((size_t)92000 * 4); size_t o = 0;
    for (int r = 0; r < NREL; ++r) { cur[r] = (int*)(base + o); o += (size_t)kNDst[r] * 4; } }
  int* csr[NREL];
  { char* base = alloc((size_t)2500000 * 4); size_t o = 0;
    for (int r = 0; r < NREL; ++r) { csr[r] = (int*)(base + o); o += (size_t)kNEdges[r] * 4; } }
  unsigned short* y[NREL];
  { char* base = alloc((size_t)92000 * OUT_F * 2); size_t o = 0;
    for (int r = 0; r < NREL; ++r) { y[r] = (unsigned short*)(base + o); o += (size_t)kNSrc[r] * OUT_F * 2; } }
  unsigned short* WT[NREL];
  { char* base = alloc((size_t)NREL * IN_F * OUT_F * 2); size_t o = 0;
    for (int r = 0; r < NREL; ++r) { WT[r] = (unsigned short*)(base + o); o += (size_t)IN_F * OUT_F * 2; } }

  hipMemsetAsync(degbase, 0, (size_t)184000 * 4, stream);

  WtParams wp;
  for (int r = 0; r < NREL; ++r) { wp.W[r] = W[r]; wp.WT[r] = WT[r]; }
  k_wt<<<dim3(64, NREL), 256, 0, stream>>>(wp);

  HistParams hp;
  for (int r = 0; r < NREL; ++r) {
    hp.j[r]        = HistJob{src[r], degO[r], kNEdges[r], kNSrc[r]};
    hp.j[NREL + r] = HistJob{dst[r], degI[r], kNEdges[r], kNDst[r]};
  }
  k_hist<<<dim3((800000 + HCHUNK - 1) / HCHUNK, 2 * NREL), 1024, 0, stream>>>(hp);

  ScanParams sp;
  for (int r = 0; r < NREL; ++r) sp.r[r] = ScanRel{degI[r], rowst[r], cur[r], kNDst[r]};
  k_scan<<<NREL, 512, 0, stream>>>(sp);

  FillParams fp;
  for (int r = 0; r < NREL; ++r) fp.r[r] = FillRel{src[r], dst[r], cur[r], csr[r], kNEdges[r], kNDst[r]};
  k_fill<<<dim3((800000 + HCHUNK - 1) / HCHUNK, NREL), 1024, 0, stream>>>(fp);

  GemmParams gp;
  for (int r = 0; r < NREL; ++r) gp.r[r] = GemmRel{h[kRelSrcType[r]], WT[r], y[r], degO[r], kNSrc[r]};
  k_gemm<<<dim3((16000 + 127) / 128, NREL), 256, 0, stream>>>(gp);

  AggParams ap;
  for (int ti = 0; ti < 4; ++ti) {
    AggType& T = ap.t[ti];
    T.n_nodes = kNNodes[ti];
    T.n_rels = kNDstRels[ti];
    T.out = out + kOutOff[ti];
    for (int j = 0; j < 4; ++j) {
      int r = kDstRels[ti][j];
      if (r < 0) r = kDstRels[ti][0];
      T.r[j] = AggRel{rowst[r], csr[r], y[r], b[r]};
    }
  }
  k_aggregate<<<dim3(16000, 4), 64, 0, stream>>>(ap);
}

// Round 4
// 217.376 us; speedup vs baseline: 3.0247x; 1.6339x over previous
//
#include <hip/hip_runtime.h>
#include <cstddef>
#include <cstdint>

#define IN_F 512
#define OUT_F 128
#define NREL 10
#define MAXBINS 16000
#define CCHUNK 16384

typedef __attribute__((ext_vector_type(8))) short short8;
typedef __attribute__((ext_vector_type(4))) float f32x4;

static const int kNSrc[NREL]   = {8000,16000,8000,16000,8000,4000,8000,4000,16000,4000};
static const int kNDst[NREL]   = {8000,16000,16000,8000,4000,8000,4000,8000,4000,16000};
static const int kNEdges[NREL] = {200000,800000,400000,400000,100000,100000,100000,100000,150000,150000};
static const int kRelSrcType[NREL] = {0,1,0,1,0,2,0,3,1,2};
static const int kNNodes[4] = {8000,16000,4000,4000};
static const size_t kOutOff[4] = {0, 8000ull*OUT_F, 24000ull*OUT_F, 28000ull*OUT_F};
static const int kDstRels[4][4] = {{0,3,5,7},{1,2,9,-1},{4,8,-1,-1},{6,-1,-1,-1}};
static const int kNDstRels[4] = {4,3,2,1};

__device__ __forceinline__ unsigned short f2bf(float f) {
  union { float f; unsigned u; } v; v.f = f;
  unsigned r = v.u + 0x7fffu + ((v.u >> 16) & 1u);
  return (unsigned short)(r >> 16);
}
__device__ __forceinline__ float bf2f(unsigned short b) {
  union { unsigned u; float f; } v; v.u = ((unsigned)b) << 16;
  return v.f;
}

// ---------------- per-chunk LDS histogram -> coalesced H rows (no global atomics) ----
struct CountJob { const int* idx; int* H; int n_edges; int nbins; };
struct CountParams { CountJob j[2 * NREL]; };

__global__ __launch_bounds__(512) void k_count(CountParams p) {
  CountJob J = p.j[blockIdx.y];
  const int e0 = blockIdx.x * CCHUNK;
  if (e0 >= J.n_edges) return;
  __shared__ int lb[MAXBINS];
  const int t = threadIdx.x;
  for (int d = t; d < J.nbins; d += 512) lb[d] = 0;
  __syncthreads();
  const int eend = (e0 + CCHUNK < J.n_edges) ? e0 + CCHUNK : J.n_edges;
  for (int e = e0 + t; e < eend; e += 512) atomicAdd(&lb[J.idx[e]], 1);
  __syncthreads();
  int* Hrow = J.H + (size_t)blockIdx.x * J.nbins;
  for (int d = t; d < J.nbins; d += 512) Hrow[d] = lb[d];
}

// ---------------- column-sum of H -> totals (deg_out / scan input), coalesced --------
struct SumJob { const int* H; int* tot; int nbins; int nblocks; };
struct SumParams { SumJob j[2 * NREL]; };

__global__ __launch_bounds__(256) void k_sum(SumParams p) {
  SumJob J = p.j[blockIdx.y];
  const int bin = blockIdx.x * 256 + threadIdx.x;
  if (bin >= J.nbins) return;
  int s = 0;
  for (int b = 0; b < J.nblocks; ++b) s += J.H[(size_t)b * J.nbins + bin];
  J.tot[bin] = s;
}

// ---------------- exclusive scan (one 512-thread block per relation, n<=16384) -------
struct ScanRel { const int* tot; int* rowstart; int n; };
struct ScanParams { ScanRel r[NREL]; };

__global__ __launch_bounds__(512) void k_scan(ScanParams p) {
  ScanRel R = p.r[blockIdx.x];
  const int t = threadIdx.x;
  const int lane = t & 63, wv = t >> 6;
  const int base = t * 32;
  int v[32];
  int s = 0;
#pragma unroll
  for (int i = 0; i < 32; ++i) {
    int e = base + i;
    int x = (e < R.n) ? R.tot[e] : 0;
    v[i] = s; s += x;
  }
  int inc = s;
#pragma unroll
  for (int off = 1; off < 64; off <<= 1) {
    int u = __shfl_up(inc, off);
    if (lane >= off) inc += u;
  }
  __shared__ int wsum[8];
  if (lane == 63) wsum[wv] = inc;
  __syncthreads();
  int carry = 0, total = 0;
#pragma unroll
  for (int w = 0; w < 8; ++w) {
    int x = wsum[w];
    if (w < wv) carry += x;
    total += x;
  }
  const int tb = carry + (inc - s);
#pragma unroll
  for (int i = 0; i < 32; ++i) {
    int e = base + i;
    if (e < R.n) R.rowstart[e] = tb + v[i];
  }
  if (t == 0) R.rowstart[R.n] = total;
}

// ---------------- per-(block,bin) bases: H becomes per-block cursor starts -----------
struct BasesJob { int* H; const int* rowstart; int nbins; int nblocks; };
struct BasesParams { BasesJob j[NREL]; };

__global__ __launch_bounds__(256) void k_bases(BasesParams p) {
  BasesJob J = p.j[blockIdx.y];
  const int bin = blockIdx.x * 256 + threadIdx.x;
  if (bin >= J.nbins) return;
  int b0 = J.rowstart[bin];
  for (int b = 0; b < J.nblocks; ++b) {
    const size_t o = (size_t)b * J.nbins + bin;
    const int c = J.H[o];
    J.H[o] = b0;
    b0 += c;
  }
}

// ---------------- place edges via LDS cursors (no global atomics) --------------------
struct PlaceJob { const int* src; const int* dst; const int* H; int* csr; int n_edges; int nbins; };
struct PlaceParams { PlaceJob j[NREL]; };

__global__ __launch_bounds__(512) void k_place(PlaceParams p) {
  PlaceJob J = p.j[blockIdx.y];
  const int e0 = blockIdx.x * CCHUNK;
  if (e0 >= J.n_edges) return;
  __shared__ int lb[MAXBINS];
  const int t = threadIdx.x;
  const int* Hrow = J.H + (size_t)blockIdx.x * J.nbins;
  for (int d = t; d < J.nbins; d += 512) lb[d] = Hrow[d];
  __syncthreads();
  const int eend = (e0 + CCHUNK < J.n_edges) ? e0 + CCHUNK : J.n_edges;
  for (int e = e0 + t; e < eend; e += 512) {
    const int d = J.dst[e];
    const int pos = atomicAdd(&lb[d], 1);
    J.csr[pos] = J.src[e];
  }
}

// ---------------- W -> W^T bf16 ----------------
struct WtParams { const float* W[NREL]; unsigned short* WT[NREL]; };

__global__ __launch_bounds__(256) void k_wt(WtParams p) {
  const int r = blockIdx.y;
  const int g = blockIdx.x * 256 + threadIdx.x;  // 0..16383
  const int k = g >> 5;
  const int n0 = (g & 31) * 4;
  const float4 w = *(const float4*)(p.W[r] + (size_t)k * OUT_F + n0);
  unsigned short* WT = p.WT[r];
  WT[(size_t)(n0 + 0) * IN_F + k] = f2bf(w.x);
  WT[(size_t)(n0 + 1) * IN_F + k] = f2bf(w.y);
  WT[(size_t)(n0 + 2) * IN_F + k] = f2bf(w.z);
  WT[(size_t)(n0 + 3) * IN_F + k] = f2bf(w.w);
}

// ---------------- y_r = (h @ W_r) * deg_out^-1/2, bf16 MFMA ----------------
struct GemmRel { const float* h; const unsigned short* WT; unsigned short* y; const int* deg_out; int n_src; };
struct GemmParams { GemmRel r[NREL]; };

__global__ __launch_bounds__(256) void k_gemm(GemmParams p) {
  GemmRel R = p.r[blockIdx.y];
  const int m0 = blockIdx.x * 128;
  if (m0 >= R.n_src) return;
  __shared__ unsigned short As[128][40];  // [m][k], padded
  __shared__ unsigned short Bs[128][40];  // [n][k]
  const int t = threadIdx.x;
  const int lane = t & 63, wid = t >> 6;
  const int wm = (wid >> 1) * 64, wn = (wid & 1) * 64;
  const int l16 = lane & 15, lk = (lane >> 4) * 8;
  const int arow = t >> 1;            // 0..127
  const int akoff = (t & 1) * 16;     // 0 or 16
  const int grA = m0 + arow;
  const bool avalid = grA < R.n_src;
  const float* hrow = R.h + (size_t)grA * IN_F;
  const unsigned short* wrow = R.WT + (size_t)arow * IN_F;

  f32x4 acc[4][4];
#pragma unroll
  for (int i = 0; i < 4; ++i)
#pragma unroll
    for (int j = 0; j < 4; ++j) acc[i][j] = (f32x4){0.f, 0.f, 0.f, 0.f};

  for (int k0 = 0; k0 < IN_F; k0 += 32) {
    float4 a0, a1, a2, a3;
    if (avalid) {
      a0 = *(const float4*)(hrow + k0 + akoff);
      a1 = *(const float4*)(hrow + k0 + akoff + 4);
      a2 = *(const float4*)(hrow + k0 + akoff + 8);
      a3 = *(const float4*)(hrow + k0 + akoff + 12);
    } else {
      a0 = a1 = a2 = a3 = make_float4(0.f, 0.f, 0.f, 0.f);
    }
    uint4 bv0 = *(const uint4*)(wrow + k0 + akoff);
    uint4 bv1 = *(const uint4*)(wrow + k0 + akoff + 8);

    uint4 A0, A1;
    A0.x = (unsigned)f2bf(a0.x) | ((unsigned)f2bf(a0.y) << 16);
    A0.y = (unsigned)f2bf(a0.z) | ((unsigned)f2bf(a0.w) << 16);
    A0.z = (unsigned)f2bf(a1.x) | ((unsigned)f2bf(a1.y) << 16);
    A0.w = (unsigned)f2bf(a1.z) | ((unsigned)f2bf(a1.w) << 16);
    A1.x = (unsigned)f2bf(a2.x) | ((unsigned)f2bf(a2.y) << 16);
    A1.y = (unsigned)f2bf(a2.z) | ((unsigned)f2bf(a2.w) << 16);
    A1.z = (unsigned)f2bf(a3.x) | ((unsigned)f2bf(a3.y) << 16);
    A1.w = (unsigned)f2bf(a3.z) | ((unsigned)f2bf(a3.w) << 16);

    __syncthreads();
    *(uint4*)&As[arow][akoff] = A0;
    *(uint4*)&As[arow][akoff + 8] = A1;
    *(uint4*)&Bs[arow][akoff] = bv0;
    *(uint4*)&Bs[arow][akoff + 8] = bv1;
    __syncthreads();

    short8 af[4], bfr[4];
#pragma unroll
    for (int f = 0; f < 4; ++f) af[f] = *(const short8*)&As[wm + f * 16 + l16][lk];
#pragma unroll
    for (int f = 0; f < 4; ++f) bfr[f] = *(const short8*)&Bs[wn + f * 16 + l16][lk];
#pragma unroll
    for (int i = 0; i < 4; ++i)
#pragma unroll
      for (int j = 0; j < 4; ++j)
        acc[i][j] = __builtin_amdgcn_mfma_f32_16x16x32_bf16(af[i], bfr[j], acc[i][j], 0, 0, 0);
  }

  const int r4 = (lane >> 4) * 4;  // C/D: col=lane&15, row=(lane>>4)*4+q
#pragma unroll
  for (int i = 0; i < 4; ++i) {
#pragma unroll
    for (int q = 0; q < 4; ++q) {
      const int row = m0 + wm + i * 16 + r4 + q;
      if (row < R.n_src) {
        const int d = R.deg_out[row];
        const float s = rsqrtf((float)(d > 1 ? d : 1));
#pragma unroll
        for (int j = 0; j < 4; ++j) {
          const int col = wn + j * 16 + l16;
          R.y[(size_t)row * OUT_F + col] = f2bf(acc[i][j][q] * s);
        }
      }
    }
  }
}

// ---------------- gather-aggregate + bias + relu (one wave per dst node) -------------
struct AggRel { const int* rowstart; const int* csr; const unsigned short* y; const float* b; };
struct AggType { AggRel r[4]; int n_rels; int n_nodes; float* out; };
struct AggParams { AggType t[4]; };

__global__ __launch_bounds__(64) void k_aggregate(AggParams p) {
  const AggType& T = p.t[blockIdx.y];
  const int node = blockIdx.x;
  if (node >= T.n_nodes) return;
  const int lane = threadIdx.x;
  const int co = lane * 2;
  float ox = 0.f, oy = 0.f;
#pragma unroll
  for (int rr = 0; rr < 4; ++rr) {
    if (rr < T.n_rels) {
      const AggRel& R = T.r[rr];
      const int lo = R.rowstart[node];
      const int hi = R.rowstart[node + 1];
      float ax = 0.f, ay = 0.f;
      int k = lo;
      for (; k + 4 <= hi; k += 4) {
        const int s0 = R.csr[k], s1 = R.csr[k + 1], s2 = R.csr[k + 2], s3 = R.csr[k + 3];
        const unsigned u0 = *(const unsigned*)(R.y + (size_t)s0 * OUT_F + co);
        const unsigned u1 = *(const unsigned*)(R.y + (size_t)s1 * OUT_F + co);
        const unsigned u2 = *(const unsigned*)(R.y + (size_t)s2 * OUT_F + co);
        const unsigned u3 = *(const unsigned*)(R.y + (size_t)s3 * OUT_F + co);
        ax += bf2f((unsigned short)u0) + bf2f((unsigned short)u1) +
              bf2f((unsigned short)u2) + bf2f((unsigned short)u3);
        ay += bf2f((unsigned short)(u0 >> 16)) + bf2f((unsigned short)(u1 >> 16)) +
              bf2f((unsigned short)(u2 >> 16)) + bf2f((unsigned short)(u3 >> 16));
      }
      for (; k < hi; ++k) {
        const int s0 = R.csr[k];
        const unsigned u0 = *(const unsigned*)(R.y + (size_t)s0 * OUT_F + co);
        ax += bf2f((unsigned short)u0);
        ay += bf2f((unsigned short)(u0 >> 16));
      }
      const int deg = hi - lo;
      const float s = rsqrtf((float)(deg > 1 ? deg : 1));
      const float2 bb = *(const float2*)(R.b + co);
      ox += ax * s + bb.x;
      oy += ay * s + bb.y;
    }
  }
  float2 o;
  o.x = ox > 0.f ? ox : 0.f;
  o.y = oy > 0.f ? oy : 0.f;
  *(float2*)(T.out + (size_t)node * OUT_F + co) = o;
}

// ---------------- host ----------------
extern "C" void kernel_launch(void* const* d_in, const int* in_sizes, int n_in,
                              void* d_out, int out_size, void* d_ws, size_t ws_size,
                              hipStream_t stream) {
  const float* h[4];
  for (int i = 0; i < 4; ++i) h[i] = (const float*)d_in[i];
  const float* W[NREL]; const float* b[NREL];
  const int* src[NREL]; const int* dst[NREL];
  for (int r = 0; r < NREL; ++r) {
    W[r]   = (const float*)d_in[4 + 2 * r];
    b[r]   = (const float*)d_in[5 + 2 * r];
    src[r] = (const int*)d_in[24 + 2 * r];
    dst[r] = (const int*)d_in[25 + 2 * r];
  }
  float* out = (float*)d_out;

  int nblk[NREL];
  for (int r = 0; r < NREL; ++r) nblk[r] = (kNEdges[r] + CCHUNK - 1) / CCHUNK;

  char* ws = (char*)d_ws;
  size_t off = 0;
  auto alloc = [&](size_t bytes) -> char* {
    char* p = ws + off;
    off = (off + bytes + 255) & ~(size_t)255;
    return p;
  };
  int* degO[NREL];   // deg_out totals
  { char* base = alloc((size_t)92000 * 4); size_t o = 0;
    for (int r = 0; r < NREL; ++r) { degO[r] = (int*)(base + o); o += (size_t)kNSrc[r] * 4; } }
  int* totI[NREL];   // deg_in totals (scan input)
  { char* base = alloc((size_t)92000 * 4); size_t o = 0;
    for (int r = 0; r < NREL; ++r) { totI[r] = (int*)(base + o); o += (size_t)kNDst[r] * 4; } }
  int* rowst[NREL];
  { char* base = alloc((size_t)(92000 + NREL) * 4); size_t o = 0;
    for (int r = 0; r < NREL; ++r) { rowst[r] = (int*)(base + o); o += (size_t)(kNDst[r] + 1) * 4; } }
  int* csr[NREL];
  { char* base = alloc((size_t)2500000 * 4); size_t o = 0;
    for (int r = 0; r < NREL; ++r) { csr[r] = (int*)(base + o); o += (size_t)kNEdges[r] * 4; } }
  int* Hsrc[NREL]; int* Hdst[NREL];
  { size_t tot = 0;
    for (int r = 0; r < NREL; ++r) tot += (size_t)nblk[r] * (kNSrc[r] + kNDst[r]);
    char* base = alloc(tot * 4); size_t o = 0;
    for (int r = 0; r < NREL; ++r) { Hsrc[r] = (int*)(base + o); o += (size_t)nblk[r] * kNSrc[r] * 4; }
    for (int r = 0; r < NREL; ++r) { Hdst[r] = (int*)(base + o); o += (size_t)nblk[r] * kNDst[r] * 4; } }
  unsigned short* y[NREL];
  { char* base = alloc((size_t)92000 * OUT_F * 2); size_t o = 0;
    for (int r = 0; r < NREL; ++r) { y[r] = (unsigned short*)(base + o); o += (size_t)kNSrc[r] * OUT_F * 2; } }
  unsigned short* WT[NREL];
  { char* base = alloc((size_t)NREL * IN_F * OUT_F * 2); size_t o = 0;
    for (int r = 0; r < NREL; ++r) { WT[r] = (unsigned short*)(base + o); o += (size_t)IN_F * OUT_F * 2; } }

  WtParams wp;
  for (int r = 0; r < NREL; ++r) { wp.W[r] = W[r]; wp.WT[r] = WT[r]; }
  k_wt<<<dim3(64, NREL), 256, 0, stream>>>(wp);

  int maxblk = 0;
  for (int r = 0; r < NREL; ++r) if (nblk[r] > maxblk) maxblk = nblk[r];

  CountParams cp;
  for (int r = 0; r < NREL; ++r) {
    cp.j[r]        = CountJob{src[r], Hsrc[r], kNEdges[r], kNSrc[r]};
    cp.j[NREL + r] = CountJob{dst[r], Hdst[r], kNEdges[r], kNDst[r]};
  }
  k_count<<<dim3(maxblk, 2 * NREL), 512, 0, stream>>>(cp);

  SumParams sp2;
  for (int r = 0; r < NREL; ++r) {
    sp2.j[r]        = SumJob{Hsrc[r], degO[r], kNSrc[r], nblk[r]};
    sp2.j[NREL + r] = SumJob{Hdst[r], totI[r], kNDst[r], nblk[r]};
  }
  k_sum<<<dim3((16000 + 255) / 256, 2 * NREL), 256, 0, stream>>>(sp2);

  ScanParams sp;
  for (int r = 0; r < NREL; ++r) sp.r[r] = ScanRel{totI[r], rowst[r], kNDst[r]};
  k_scan<<<NREL, 512, 0, stream>>>(sp);

  BasesParams bp;
  for (int r = 0; r < NREL; ++r) bp.j[r] = BasesJob{Hdst[r], rowst[r], kNDst[r], nblk[r]};
  k_bases<<<dim3((16000 + 255) / 256, NREL), 256, 0, stream>>>(bp);

  PlaceParams pp;
  for (int r = 0; r < NREL; ++r) pp.j[r] = PlaceJob{src[r], dst[r], Hdst[r], csr[r], kNEdges[r], kNDst[r]};
  k_place<<<dim3(maxblk, NREL), 512, 0, stream>>>(pp);

  GemmParams gp;
  for (int r = 0; r < NREL; ++r) gp.r[r] = GemmRel{h[kRelSrcType[r]], WT[r], y[r], degO[r], kNSrc[r]};
  k_gemm<<<dim3((16000 + 127) / 128, NREL), 256, 0, stream>>>(gp);

  AggParams ap;
  for (int ti = 0; ti < 4; ++ti) {
    AggType& T = ap.t[ti];
    T.n_nodes = kNNodes[ti];
    T.n_rels = kNDstRels[ti];
    T.out = out + kOutOff[ti];
    for (int j = 0; j < 4; ++j) {
      int r = kDstRels[ti][j];
      if (r < 0) r = kDstRels[ti][0];
      T.r[j] = AggRel{rowst[r], csr[r], y[r], b[r]};
    }
  }
  k_aggregate<<<dim3(16000, 4), 64, 0, stream>>>(ap);
}